// Round 2
// baseline (880.061 us; speedup 1.0000x reference)
//
#include <hip/hip_runtime.h>

#define NB 1024
#define N1P 116
#define N2P 200
#define NN1 (NB * N1P)      // 118784
#define NN2 (NB * N2P)      // 204800
#define HD 32

// ---------------------------------------------------------------------------
// GEMM: out[N,32] = X[N,K] @ W[K,32].  Block tile: 128 rows x 32 cols.
// 256 threads, each computes 4 rows (stride 32) x 4 cols.  K chunked by 32,
// zero-padded tails.  LDS: sX[128][36] (padded), sW[32][32].
// __launch_bounds__(256,4): cap VGPR at 128 (R1 post-mortem: full K-loop
// unroll spilled at VGPR=256 -> 420 MB scratch traffic, 268 us/dispatch).
// ---------------------------------------------------------------------------
template <int K>
__global__ __launch_bounds__(256, 4) void gemm32(const float* __restrict__ X,
                                                 const float* __restrict__ W,
                                                 float* __restrict__ out) {
    constexpr int KC = 32;
    constexpr int SX = KC + 4;
    __shared__ float sX[128 * SX];
    __shared__ float sW[KC * 32];

    const int tid = threadIdx.x;
    const long row0 = (long)blockIdx.x * 128;

    const int hg = tid & 7;          // 8 h-groups of 4
    const int rg = tid >> 3;         // 32 row-groups; rows rg + 32*i
    const int h0 = hg * 4;

    const int lj = tid & 31;         // loader: col 0..31
    const int lr = tid >> 5;         // loader: row 0..7 (+8 per pass)

    float acc[4][4];
#pragma unroll
    for (int i = 0; i < 4; ++i)
#pragma unroll
        for (int c = 0; c < 4; ++c) acc[i][c] = 0.f;

#pragma unroll 1   // R1: do NOT unroll K-chunks — unrolling spilled to scratch
    for (int kc0 = 0; kc0 < K; kc0 += KC) {
        // stage x chunk: 128 rows x 32 k (zero-padded past K)
        {
            const int k = kc0 + lj;
            const bool ok = (k < K);
#pragma unroll
            for (int p = 0; p < 16; ++p) {
                const int r = lr + 8 * p;
                sX[r * SX + lj] = ok ? X[(row0 + r) * (long)K + k] : 0.f;
            }
        }
        // stage W chunk: 32 k x 32 h
#pragma unroll
        for (int p = 0; p < 4; ++p) {
            const int idx = tid + 256 * p;
            const int kk = idx >> 5, jj = idx & 31;
            const int k = kc0 + kk;
            sW[kk * 32 + jj] = (k < K) ? W[(long)k * 32 + jj] : 0.f;
        }
        __syncthreads();

#pragma unroll
        for (int j2 = 0; j2 < KC; j2 += 4) {
            float4 wv0 = *(const float4*)&sW[(j2 + 0) * 32 + h0];
            float4 wv1 = *(const float4*)&sW[(j2 + 1) * 32 + h0];
            float4 wv2 = *(const float4*)&sW[(j2 + 2) * 32 + h0];
            float4 wv3 = *(const float4*)&sW[(j2 + 3) * 32 + h0];
#pragma unroll
            for (int i = 0; i < 4; ++i) {
                float4 xv = *(const float4*)&sX[(rg + 32 * i) * SX + j2];
                acc[i][0] += xv.x * wv0.x + xv.y * wv1.x + xv.z * wv2.x + xv.w * wv3.x;
                acc[i][1] += xv.x * wv0.y + xv.y * wv1.y + xv.z * wv2.y + xv.w * wv3.y;
                acc[i][2] += xv.x * wv0.z + xv.y * wv1.z + xv.z * wv2.z + xv.w * wv3.z;
                acc[i][3] += xv.x * wv0.w + xv.y * wv1.w + xv.z * wv2.w + xv.w * wv3.w;
            }
        }
        __syncthreads();
    }

#pragma unroll
    for (int i = 0; i < 4; ++i) {
        const long r = row0 + rg + 32 * i;
        float4 o;
        o.x = acc[i][0]; o.y = acc[i][1]; o.z = acc[i][2]; o.w = acc[i][3];
        *(float4*)&out[r * 32 + h0] = o;
    }
}

// ---------------------------------------------------------------------------
// Aggregation: out[i,h] = relu(b[h] + sum_{k<16} vals[i*16+k]*sup[cols[i*16+k],h])
// rows are contiguous (node i owns edges [i*16, i*16+16)).  8 nodes/block.
// ---------------------------------------------------------------------------
__global__ __launch_bounds__(256) void agg_relu(const int* __restrict__ cols,
                                                const float* __restrict__ vals,
                                                const float* __restrict__ sup,
                                                const float* __restrict__ bias,
                                                float* __restrict__ out) {
    const int tid = threadIdx.x;
    const int h = tid & 31;
    const long i = (long)blockIdx.x * 8 + (tid >> 5);
    const long e0 = i * 16;
    float acc = bias[h];
#pragma unroll
    for (int k = 0; k < 16; ++k) {
        const int c = cols[e0 + k];
        const float v = vals[e0 + k];
        acc += v * sup[(long)c * 32 + h];
    }
    out[i * 32 + h] = fmaxf(acc, 0.f);
}

// ---------------------------------------------------------------------------
// Per-graph mean+max pool over nodes.  grid = B, block = 256 (32 h x 8 slices)
// feats layout per graph: [mean_b1(32) max_b1(32) mean_b2(32) max_b2(32)]
// ---------------------------------------------------------------------------
template <int NPER>
__global__ __launch_bounds__(256) void pool_meanmax(const float* __restrict__ hin,
                                                    float* __restrict__ feats,
                                                    int foff) {
    const int g = blockIdx.x;
    const int tid = threadIdx.x;
    const int h = tid & 31, s = tid >> 5;
    const float* base = hin + (long)g * NPER * 32;
    float sum = 0.f, mx = -1e30f;
    for (int n = s; n < NPER; n += 8) {
        const float v = base[n * 32 + h];
        sum += v;
        mx = fmaxf(mx, v);
    }
    __shared__ float sS[256], sM[256];
    sS[tid] = sum;
    sM[tid] = mx;
    __syncthreads();
    if (tid < 32) {
#pragma unroll
        for (int q = 1; q < 8; ++q) {
            sum += sS[tid + 32 * q];
            mx = fmaxf(mx, sM[tid + 32 * q]);
        }
        feats[(long)g * 128 + foff + h] = sum * (1.0f / NPER);
        feats[(long)g * 128 + foff + 32 + h] = mx;
    }
}

// ---------------------------------------------------------------------------
// MLP head: [B,128] -> relu(fc1) -> relu(fc2) -> fc3 -> [B,2]
// 8 graphs per block (32 lanes each).
// ---------------------------------------------------------------------------
__global__ __launch_bounds__(256) void mlp_head(const float* __restrict__ feats,
                                                const float* __restrict__ W1,
                                                const float* __restrict__ b1,
                                                const float* __restrict__ W2,
                                                const float* __restrict__ b2,
                                                const float* __restrict__ W3,
                                                const float* __restrict__ b3,
                                                float* __restrict__ out) {
    __shared__ float sW1[128 * 32];
    __shared__ float sW2[32 * 16];
    __shared__ float sW3[16 * 2];
    __shared__ float sB1[32], sB2[16], sB3[2];
    __shared__ float sF[8 * 128];
    __shared__ float sH1[8 * 32];
    __shared__ float sH2[8 * 16];

    const int tid = threadIdx.x;
    for (int idx = tid; idx < 128 * 32; idx += 256) sW1[idx] = W1[idx];
    for (int idx = tid; idx < 32 * 16; idx += 256) sW2[idx] = W2[idx];
    if (tid < 32) { sW3[tid] = W3[tid]; sB1[tid] = b1[tid]; }
    if (tid < 16) sB2[tid] = b2[tid];
    if (tid < 2) sB3[tid] = b3[tid];
    const long g0 = (long)blockIdx.x * 8;
    for (int idx = tid; idx < 1024; idx += 256) sF[idx] = feats[g0 * 128 + idx];
    __syncthreads();

    const int g = tid >> 5, h = tid & 31;
    float a1 = sB1[h];
#pragma unroll 4
    for (int k = 0; k < 128; ++k) a1 += sF[g * 128 + k] * sW1[k * 32 + h];
    sH1[g * 32 + h] = fmaxf(a1, 0.f);
    __syncthreads();

    if (h < 16) {
        float a2 = sB2[h];
#pragma unroll
        for (int k = 0; k < 32; ++k) a2 += sH1[g * 32 + k] * sW2[k * 16 + h];
        sH2[g * 16 + h] = fmaxf(a2, 0.f);
    }
    __syncthreads();

    if (h < 2) {
        float a3 = sB3[h];
#pragma unroll
        for (int k = 0; k < 16; ++k) a3 += sH2[g * 16 + k] * sW3[k * 2 + h];
        out[(g0 + g) * 2 + h] = a3;
    }
}

// ---------------------------------------------------------------------------
extern "C" void kernel_launch(void* const* d_in, const int* in_sizes, int n_in,
                              void* d_out, int out_size, void* d_ws, size_t ws_size,
                              hipStream_t stream) {
    const int*   cols1 = (const int*)d_in[1];
    const float* vals1 = (const float*)d_in[2];
    const float* x1    = (const float*)d_in[3];
    const int*   cols2 = (const int*)d_in[5];
    const float* vals2 = (const float*)d_in[6];
    const float* x2    = (const float*)d_in[7];
    const float* W1a = (const float*)d_in[8];
    const float* b1a = (const float*)d_in[9];
    const float* W1b = (const float*)d_in[10];
    const float* b1b = (const float*)d_in[11];
    const float* W2a = (const float*)d_in[12];
    const float* b2a = (const float*)d_in[13];
    const float* W2b = (const float*)d_in[14];
    const float* b2b = (const float*)d_in[15];
    const float* fc1_W = (const float*)d_in[16];
    const float* fc1_b = (const float*)d_in[17];
    const float* fc2_W = (const float*)d_in[18];
    const float* fc2_b = (const float*)d_in[19];
    const float* fc3_W = (const float*)d_in[20];
    const float* fc3_b = (const float*)d_in[21];
    float* out = (float*)d_out;

    float* sup   = (float*)d_ws;
    float* hbuf  = sup + (size_t)NN2 * 32;
    float* feats = hbuf + (size_t)NN2 * 32;

    // ---- branch 1 (116) ----
    gemm32<N1P><<<NN1 / 128, 256, 0, stream>>>(x1, W1a, sup);
    agg_relu<<<NN1 / 8, 256, 0, stream>>>(cols1, vals1, sup, b1a, hbuf);
    gemm32<HD><<<NN1 / 128, 256, 0, stream>>>(hbuf, W1b, sup);
    agg_relu<<<NN1 / 8, 256, 0, stream>>>(cols1, vals1, sup, b1b, hbuf);
    pool_meanmax<N1P><<<NB, 256, 0, stream>>>(hbuf, feats, 0);

    // ---- branch 2 (200) ----
    gemm32<N2P><<<NN2 / 128, 256, 0, stream>>>(x2, W2a, sup);
    agg_relu<<<NN2 / 8, 256, 0, stream>>>(cols2, vals2, sup, b2a, hbuf);
    gemm32<HD><<<NN2 / 128, 256, 0, stream>>>(hbuf, W2b, sup);
    agg_relu<<<NN2 / 8, 256, 0, stream>>>(cols2, vals2, sup, b2b, hbuf);
    pool_meanmax<N2P><<<NB, 256, 0, stream>>>(hbuf, feats, 64);

    // ---- MLP head ----
    mlp_head<<<NB / 8, 256, 0, stream>>>(feats, fc1_W, fc1_b, fc2_W, fc2_b,
                                         fc3_W, fc3_b, out);
}

// Round 3
// 622.474 us; speedup vs baseline: 1.4138x; 1.4138x over previous
//
#include <hip/hip_runtime.h>

#define NB 1024
#define N1P 116
#define N2P 200
#define NN1 (NB * N1P)      // 118784
#define NN2 (NB * N2P)      // 204800
#define HD 32

// ---------------------------------------------------------------------------
// GEMM: out[N,32] = X[N,K] @ W[K,32].  R3 structure: NO X staging.
// W (K x 32 <= 25.6 KB) lives entirely in LDS (one barrier).  Each thread
// streams 4 complete X rows from global (aligned float4; row stride K*4 B is
// 16B-aligned for K in {32,116,200}) and holds a 4x8 register tile.
// Block = 256 threads = 64 row-groups x 4 h-groups -> 256 rows/block.
// LDS W reads: 2 b128 per k, 4 unique addrs/instr at 32B spacing ->
// disjoint bank quads, conflict-free, broadcast across row-lanes.
// R1/R2 lesson: keep '#pragma unroll 1' on the k-loop (unroll => spill).
// ---------------------------------------------------------------------------
template <int K>
__global__ __launch_bounds__(256, 4) void gemm32s(const float* __restrict__ X,
                                                  const float* __restrict__ W,
                                                  float* __restrict__ out) {
    __shared__ float sW[K * 32];
    const int tid = threadIdx.x;
    for (int idx = tid; idx < K * 32; idx += 256) sW[idx] = W[idx];
    __syncthreads();

    const int hg = tid & 3;          // 4 h-groups of 8
    const int h0 = hg * 8;
    const long row0 = (long)blockIdx.x * 256 + (tid >> 2) * 4;  // 4 rows/thread

    const float* xp[4];
#pragma unroll
    for (int r = 0; r < 4; ++r) xp[r] = X + (row0 + r) * (long)K;

    float acc[4][8];
#pragma unroll
    for (int r = 0; r < 4; ++r)
#pragma unroll
        for (int c = 0; c < 8; ++c) acc[r][c] = 0.f;

    constexpr int KJ = K / 4;   // K % 4 == 0 for 32/116/200

    float4 xc[4];
#pragma unroll
    for (int r = 0; r < 4; ++r) xc[r] = *(const float4*)xp[r];

#pragma unroll 1
    for (int kj = 0; kj < KJ; ++kj) {
        // prefetch next k-chunk of the 4 rows
        float4 xn[4];
        if (kj + 1 < KJ) {
#pragma unroll
            for (int r = 0; r < 4; ++r)
                xn[r] = *(const float4*)(xp[r] + (kj + 1) * 4);
        } else {
#pragma unroll
            for (int r = 0; r < 4; ++r) xn[r] = make_float4(0.f, 0.f, 0.f, 0.f);
        }

        const float* wb = &sW[kj * 4 * 32 + h0];
#pragma unroll
        for (int kk = 0; kk < 4; ++kk) {
            const float4 w0 = *(const float4*)&wb[kk * 32];
            const float4 w1 = *(const float4*)&wb[kk * 32 + 4];
#pragma unroll
            for (int r = 0; r < 4; ++r) {
                const float xs = ((const float*)&xc[r])[kk];
                acc[r][0] += xs * w0.x;
                acc[r][1] += xs * w0.y;
                acc[r][2] += xs * w0.z;
                acc[r][3] += xs * w0.w;
                acc[r][4] += xs * w1.x;
                acc[r][5] += xs * w1.y;
                acc[r][6] += xs * w1.z;
                acc[r][7] += xs * w1.w;
            }
        }
#pragma unroll
        for (int r = 0; r < 4; ++r) xc[r] = xn[r];
    }

#pragma unroll
    for (int r = 0; r < 4; ++r) {
        const long row = row0 + r;
        float4 o0, o1;
        o0.x = acc[r][0]; o0.y = acc[r][1]; o0.z = acc[r][2]; o0.w = acc[r][3];
        o1.x = acc[r][4]; o1.y = acc[r][5]; o1.z = acc[r][6]; o1.w = acc[r][7];
        *(float4*)&out[row * 32 + h0] = o0;
        *(float4*)&out[row * 32 + h0 + 4] = o1;
    }
}

// ---------------------------------------------------------------------------
// Aggregation: out[i,h] = relu(b[h] + sum_{k<16} vals[i*16+k]*sup[cols[i*16+k],h])
// rows contiguous (node i owns edges [i*16, i*16+16)).  8 nodes/block.
// cols/vals loaded as int4/float4 (64B-aligned since i*16 ints = 64 B).
// ---------------------------------------------------------------------------
__global__ __launch_bounds__(256) void agg_relu(const int* __restrict__ cols,
                                                const float* __restrict__ vals,
                                                const float* __restrict__ sup,
                                                const float* __restrict__ bias,
                                                float* __restrict__ out) {
    const int tid = threadIdx.x;
    const int h = tid & 31;
    const long i = (long)blockIdx.x * 8 + (tid >> 5);
    const int4* c4 = (const int4*)(cols + i * 16);
    const float4* v4 = (const float4*)(vals + i * 16);
    float acc = bias[h];
#pragma unroll
    for (int q = 0; q < 4; ++q) {
        const int4 c = c4[q];
        const float4 v = v4[q];
        acc += v.x * sup[(long)c.x * 32 + h];
        acc += v.y * sup[(long)c.y * 32 + h];
        acc += v.z * sup[(long)c.z * 32 + h];
        acc += v.w * sup[(long)c.w * 32 + h];
    }
    out[i * 32 + h] = fmaxf(acc, 0.f);
}

// ---------------------------------------------------------------------------
// Per-graph mean+max pool.  grid = B, block = 256 (32 h x 8 slices)
// feats layout per graph: [mean_b1(32) max_b1(32) mean_b2(32) max_b2(32)]
// ---------------------------------------------------------------------------
template <int NPER>
__global__ __launch_bounds__(256) void pool_meanmax(const float* __restrict__ hin,
                                                    float* __restrict__ feats,
                                                    int foff) {
    const int g = blockIdx.x;
    const int tid = threadIdx.x;
    const int h = tid & 31, s = tid >> 5;
    const float* base = hin + (long)g * NPER * 32;
    float sum = 0.f, mx = -1e30f;
    for (int n = s; n < NPER; n += 8) {
        const float v = base[n * 32 + h];
        sum += v;
        mx = fmaxf(mx, v);
    }
    __shared__ float sS[256], sM[256];
    sS[tid] = sum;
    sM[tid] = mx;
    __syncthreads();
    if (tid < 32) {
#pragma unroll
        for (int q = 1; q < 8; ++q) {
            sum += sS[tid + 32 * q];
            mx = fmaxf(mx, sM[tid + 32 * q]);
        }
        feats[(long)g * 128 + foff + h] = sum * (1.0f / NPER);
        feats[(long)g * 128 + foff + 32 + h] = mx;
    }
}

// ---------------------------------------------------------------------------
// MLP head: [B,128] -> relu(fc1) -> relu(fc2) -> fc3 -> [B,2]
// ---------------------------------------------------------------------------
__global__ __launch_bounds__(256) void mlp_head(const float* __restrict__ feats,
                                                const float* __restrict__ W1,
                                                const float* __restrict__ b1,
                                                const float* __restrict__ W2,
                                                const float* __restrict__ b2,
                                                const float* __restrict__ W3,
                                                const float* __restrict__ b3,
                                                float* __restrict__ out) {
    __shared__ float sW1[128 * 32];
    __shared__ float sW2[32 * 16];
    __shared__ float sW3[16 * 2];
    __shared__ float sB1[32], sB2[16], sB3[2];
    __shared__ float sF[8 * 128];
    __shared__ float sH1[8 * 32];
    __shared__ float sH2[8 * 16];

    const int tid = threadIdx.x;
    for (int idx = tid; idx < 128 * 32; idx += 256) sW1[idx] = W1[idx];
    for (int idx = tid; idx < 32 * 16; idx += 256) sW2[idx] = W2[idx];
    if (tid < 32) { sW3[tid] = W3[tid]; sB1[tid] = b1[tid]; }
    if (tid < 16) sB2[tid] = b2[tid];
    if (tid < 2) sB3[tid] = b3[tid];
    const long g0 = (long)blockIdx.x * 8;
    for (int idx = tid; idx < 1024; idx += 256) sF[idx] = feats[g0 * 128 + idx];
    __syncthreads();

    const int g = tid >> 5, h = tid & 31;
    float a1 = sB1[h];
#pragma unroll 4
    for (int k = 0; k < 128; ++k) a1 += sF[g * 128 + k] * sW1[k * 32 + h];
    sH1[g * 32 + h] = fmaxf(a1, 0.f);
    __syncthreads();

    if (h < 16) {
        float a2 = sB2[h];
#pragma unroll
        for (int k = 0; k < 32; ++k) a2 += sH1[g * 32 + k] * sW2[k * 16 + h];
        sH2[g * 16 + h] = fmaxf(a2, 0.f);
    }
    __syncthreads();

    if (h < 2) {
        float a3 = sB3[h];
#pragma unroll
        for (int k = 0; k < 16; ++k) a3 += sH2[g * 16 + k] * sW3[k * 2 + h];
        out[(g0 + g) * 2 + h] = a3;
    }
}

// ---------------------------------------------------------------------------
extern "C" void kernel_launch(void* const* d_in, const int* in_sizes, int n_in,
                              void* d_out, int out_size, void* d_ws, size_t ws_size,
                              hipStream_t stream) {
    const int*   cols1 = (const int*)d_in[1];
    const float* vals1 = (const float*)d_in[2];
    const float* x1    = (const float*)d_in[3];
    const int*   cols2 = (const int*)d_in[5];
    const float* vals2 = (const float*)d_in[6];
    const float* x2    = (const float*)d_in[7];
    const float* W1a = (const float*)d_in[8];
    const float* b1a = (const float*)d_in[9];
    const float* W1b = (const float*)d_in[10];
    const float* b1b = (const float*)d_in[11];
    const float* W2a = (const float*)d_in[12];
    const float* b2a = (const float*)d_in[13];
    const float* W2b = (const float*)d_in[14];
    const float* b2b = (const float*)d_in[15];
    const float* fc1_W = (const float*)d_in[16];
    const float* fc1_b = (const float*)d_in[17];
    const float* fc2_W = (const float*)d_in[18];
    const float* fc2_b = (const float*)d_in[19];
    const float* fc3_W = (const float*)d_in[20];
    const float* fc3_b = (const float*)d_in[21];
    float* out = (float*)d_out;

    float* sup   = (float*)d_ws;
    float* hbuf  = sup + (size_t)NN2 * 32;
    float* feats = hbuf + (size_t)NN2 * 32;

    // ---- branch 1 (116) ----   NN1/256 = 464 blocks
    gemm32s<N1P><<<NN1 / 256, 256, 0, stream>>>(x1, W1a, sup);
    agg_relu<<<NN1 / 8, 256, 0, stream>>>(cols1, vals1, sup, b1a, hbuf);
    gemm32s<HD><<<NN1 / 256, 256, 0, stream>>>(hbuf, W1b, sup);
    agg_relu<<<NN1 / 8, 256, 0, stream>>>(cols1, vals1, sup, b1b, hbuf);
    pool_meanmax<N1P><<<NB, 256, 0, stream>>>(hbuf, feats, 0);

    // ---- branch 2 (200) ----   NN2/256 = 800 blocks
    gemm32s<N2P><<<NN2 / 256, 256, 0, stream>>>(x2, W2a, sup);
    agg_relu<<<NN2 / 8, 256, 0, stream>>>(cols2, vals2, sup, b2a, hbuf);
    gemm32s<HD><<<NN2 / 256, 256, 0, stream>>>(hbuf, W2b, sup);
    agg_relu<<<NN2 / 8, 256, 0, stream>>>(cols2, vals2, sup, b2b, hbuf);
    pool_meanmax<N2P><<<NB, 256, 0, stream>>>(hbuf, feats, 64);

    // ---- MLP head ----
    mlp_head<<<NB / 8, 256, 0, stream>>>(feats, fc1_W, fc1_b, fc2_W, fc2_b,
                                         fc3_W, fc3_b, out);
}

// Round 4
// 535.863 us; speedup vs baseline: 1.6423x; 1.1616x over previous
//
#include <hip/hip_runtime.h>

#define NB 1024
#define N1P 116
#define N2P 200
#define HD 32

// ---------------------------------------------------------------------------
// Fully fused per-graph branch: one block = one graph.
//   L1: support = X_g @ Wa   (X_g staged coalesced in k-chunks into LDS;
//       thread = node row, computes all 32 cols; W via uniform s_loads)
//   agg1+relu -> h1 (LDS)    (bank = h -> conflict-free)
//   L2: support2 = h1 @ Wb   (same row-per-thread scheme)
//   agg2+relu -> h2 (LDS)
//   pool mean+max -> feats[g*128 + foff .. +63]
// LDS: sSup (NP*32) + sH (NP*32) = 51.2 KB max -> 3 blocks/CU.
// X-stage buffer (NP*20 floats, stride 20 = 8-way-max bank spread) ALIASES
// sSup: sup is only written after the last X chunk is consumed.
// ---------------------------------------------------------------------------

__device__ __forceinline__ void agg_phase(int base, int NPv,
                                          const int* __restrict__ cols,
                                          const float* __restrict__ vals,
                                          const float* __restrict__ sup,
                                          float bias, float* __restrict__ outh,
                                          int tid) {
    const int h = tid & 31;
    for (int n = tid >> 5; n < NPv; n += 8) {
        const int4* c4 = (const int4*)(cols + ((size_t)base + n) * 16);
        const float4* v4 = (const float4*)(vals + ((size_t)base + n) * 16);
        float a = bias;
#pragma unroll
        for (int q = 0; q < 4; ++q) {
            const int4 c = c4[q];
            const float4 v = v4[q];
            a += v.x * sup[(c.x - base) * 32 + h];
            a += v.y * sup[(c.y - base) * 32 + h];
            a += v.z * sup[(c.z - base) * 32 + h];
            a += v.w * sup[(c.w - base) * 32 + h];
        }
        outh[n * 32 + h] = fmaxf(a, 0.f);
    }
}

// row-per-thread GEMM from LDS x (stride SXS) against global W (uniform loads)
template <int NK>
__device__ __forceinline__ void row_gemm_acc(float* acc, const float* __restrict__ xrow,
                                             const float* __restrict__ W) {
#pragma unroll 1
    for (int k4 = 0; k4 < NK; k4 += 4) {
        const float4 x4 = *(const float4*)&xrow[k4];
#pragma unroll
        for (int kk = 0; kk < 4; ++kk) {
            const float xs = (&x4.x)[kk];
            const float* w = W + (k4 + kk) * 32;
#pragma unroll
            for (int c4 = 0; c4 < 8; ++c4) {
                const float4 wv = *(const float4*)&w[c4 * 4];
                acc[c4 * 4 + 0] += xs * wv.x;
                acc[c4 * 4 + 1] += xs * wv.y;
                acc[c4 * 4 + 2] += xs * wv.z;
                acc[c4 * 4 + 3] += xs * wv.w;
            }
        }
    }
}

template <int NP>
__device__ void branch_graph(int g,
                             const float* __restrict__ X,
                             const int* __restrict__ cols,
                             const float* __restrict__ vals,
                             const float* __restrict__ Wa,
                             const float* __restrict__ ba,
                             const float* __restrict__ Wb,
                             const float* __restrict__ bb,
                             float* __restrict__ feats, int foff,
                             float* sSup, float* sH) {
    const int tid = threadIdx.x;
    const int base = g * NP;
    const float* xg = X + (size_t)base * NP;   // contiguous NP x NP block
    const float bA = ba[tid & 31];
    const float bB = bb[tid & 31];

    // ---- L1 GEMM: support = X_g @ Wa, k-chunked (KC=16), sX aliases sSup ----
    constexpr int KC = 16;
    constexpr int SXS = 20;                    // LDS row stride: 8-way max spread
    float* sX = sSup;                          // NP*20 floats <= NP*32 ok
    float acc[32];
#pragma unroll
    for (int c = 0; c < 32; ++c) acc[c] = 0.f;

    const int NC = (NP + KC - 1) / KC;
#pragma unroll 1
    for (int kc = 0; kc < NC; ++kc) {
        const int k0 = kc * KC;
        const int kw = (NP - k0) < KC ? (NP - k0) : KC;   // multiple of 4
        const int pieces = kw >> 2;
        // coalesced stage: graph block rows, 16B pieces
        for (int i = tid; i < NP * 4; i += 256) {
            const int row = i >> 2, p = i & 3;
            if (p < pieces) {
                const float4 v = *(const float4*)(xg + (size_t)row * NP + k0 + p * 4);
                *(float4*)&sX[row * SXS + p * 4] = v;
            }
        }
        __syncthreads();
        if (tid < NP) {
            const float* wbase = Wa + k0 * 32;
            const float* xrow = &sX[tid * SXS];
#pragma unroll 1
            for (int k4 = 0; k4 < kw; k4 += 4) {
                const float4 x4 = *(const float4*)&xrow[k4];
#pragma unroll
                for (int kk = 0; kk < 4; ++kk) {
                    const float xs = (&x4.x)[kk];
                    const float* w = wbase + (k4 + kk) * 32;
#pragma unroll
                    for (int c4 = 0; c4 < 8; ++c4) {
                        const float4 wv = *(const float4*)&w[c4 * 4];
                        acc[c4 * 4 + 0] += xs * wv.x;
                        acc[c4 * 4 + 1] += xs * wv.y;
                        acc[c4 * 4 + 2] += xs * wv.z;
                        acc[c4 * 4 + 3] += xs * wv.w;
                    }
                }
            }
        }
        __syncthreads();   // before next chunk overwrites sX
    }
    // write support (sX dead now; same buffer, full stride-32 layout)
    if (tid < NP) {
#pragma unroll
        for (int c4 = 0; c4 < 8; ++c4) {
            float4 o;
            o.x = acc[c4 * 4 + 0]; o.y = acc[c4 * 4 + 1];
            o.z = acc[c4 * 4 + 2]; o.w = acc[c4 * 4 + 3];
            *(float4*)&sSup[tid * 32 + c4 * 4] = o;
        }
    }
    __syncthreads();

    // ---- agg1 + relu -> sH ----
    agg_phase(base, NP, cols, vals, sSup, bA, sH, tid);
    __syncthreads();

    // ---- L2 GEMM: support2 = h1 @ Wb -> sSup ----
    if (tid < NP) {
        float acc2[32];
#pragma unroll
        for (int c = 0; c < 32; ++c) acc2[c] = 0.f;
        row_gemm_acc<32>(acc2, &sH[tid * 32], Wb);
#pragma unroll
        for (int c4 = 0; c4 < 8; ++c4) {
            float4 o;
            o.x = acc2[c4 * 4 + 0]; o.y = acc2[c4 * 4 + 1];
            o.z = acc2[c4 * 4 + 2]; o.w = acc2[c4 * 4 + 3];
            *(float4*)&sSup[tid * 32 + c4 * 4] = o;
        }
    }
    __syncthreads();

    // ---- agg2 + relu -> sH (h1 dead) ----
    agg_phase(base, NP, cols, vals, sSup, bB, sH, tid);
    __syncthreads();

    // ---- pool mean+max over nodes ----
    const int h = tid & 31, sl = tid >> 5;
    float sum = 0.f, mx = -1e30f;
    for (int n = sl; n < NP; n += 8) {
        const float v = sH[n * 32 + h];
        sum += v;
        mx = fmaxf(mx, v);
    }
    // scratch over sSup (support2 dead)
    float* sS = sSup;
    float* sM = sSup + 256;
    sS[tid] = sum;
    sM[tid] = mx;
    __syncthreads();
    if (tid < 32) {
#pragma unroll
        for (int q = 1; q < 8; ++q) {
            sum += sS[tid + 32 * q];
            mx = fmaxf(mx, sM[tid + 32 * q]);
        }
        feats[(size_t)g * 128 + foff + tid] = sum * (1.0f / NP);
        feats[(size_t)g * 128 + foff + 32 + tid] = mx;
    }
}

__global__ __launch_bounds__(256, 2) void fused_branches(
        const float* __restrict__ x1, const int* __restrict__ cols1,
        const float* __restrict__ vals1,
        const float* __restrict__ W1a, const float* __restrict__ b1a,
        const float* __restrict__ W1b, const float* __restrict__ b1b,
        const float* __restrict__ x2, const int* __restrict__ cols2,
        const float* __restrict__ vals2,
        const float* __restrict__ W2a, const float* __restrict__ b2a,
        const float* __restrict__ W2b, const float* __restrict__ b2b,
        float* __restrict__ feats) {
    __shared__ float sSup[N2P * 32];   // 25.6 KB
    __shared__ float sH[N2P * 32];     // 25.6 KB  (total 51.2 KB -> 3 blocks/CU)
    const int bid = blockIdx.x;
    if (bid < NB) {
        branch_graph<N1P>(bid, x1, cols1, vals1, W1a, b1a, W1b, b1b, feats, 0,
                          sSup, sH);
    } else {
        branch_graph<N2P>(bid - NB, x2, cols2, vals2, W2a, b2a, W2b, b2b, feats,
                          64, sSup, sH);
    }
}

// ---------------------------------------------------------------------------
// MLP head: [B,128] -> relu(fc1) -> relu(fc2) -> fc3 -> [B,2]
// ---------------------------------------------------------------------------
__global__ __launch_bounds__(256) void mlp_head(const float* __restrict__ feats,
                                                const float* __restrict__ W1,
                                                const float* __restrict__ b1,
                                                const float* __restrict__ W2,
                                                const float* __restrict__ b2,
                                                const float* __restrict__ W3,
                                                const float* __restrict__ b3,
                                                float* __restrict__ out) {
    __shared__ float sW1[128 * 32];
    __shared__ float sW2[32 * 16];
    __shared__ float sW3[16 * 2];
    __shared__ float sB1[32], sB2[16], sB3[2];
    __shared__ float sF[8 * 128];
    __shared__ float sH1[8 * 32];
    __shared__ float sH2[8 * 16];

    const int tid = threadIdx.x;
    for (int idx = tid; idx < 128 * 32; idx += 256) sW1[idx] = W1[idx];
    for (int idx = tid; idx < 32 * 16; idx += 256) sW2[idx] = W2[idx];
    if (tid < 32) { sW3[tid] = W3[tid]; sB1[tid] = b1[tid]; }
    if (tid < 16) sB2[tid] = b2[tid];
    if (tid < 2) sB3[tid] = b3[tid];
    const long g0 = (long)blockIdx.x * 8;
    for (int idx = tid; idx < 1024; idx += 256) sF[idx] = feats[g0 * 128 + idx];
    __syncthreads();

    const int g = tid >> 5, h = tid & 31;
    float a1 = sB1[h];
#pragma unroll 4
    for (int k = 0; k < 128; ++k) a1 += sF[g * 128 + k] * sW1[k * 32 + h];
    sH1[g * 32 + h] = fmaxf(a1, 0.f);
    __syncthreads();

    if (h < 16) {
        float a2 = sB2[h];
#pragma unroll
        for (int k = 0; k < 32; ++k) a2 += sH1[g * 32 + k] * sW2[k * 16 + h];
        sH2[g * 16 + h] = fmaxf(a2, 0.f);
    }
    __syncthreads();

    if (h < 2) {
        float a3 = sB3[h];
#pragma unroll
        for (int k = 0; k < 16; ++k) a3 += sH2[g * 16 + k] * sW3[k * 2 + h];
        out[(g0 + g) * 2 + h] = a3;
    }
}

// ---------------------------------------------------------------------------
extern "C" void kernel_launch(void* const* d_in, const int* in_sizes, int n_in,
                              void* d_out, int out_size, void* d_ws, size_t ws_size,
                              hipStream_t stream) {
    const int*   cols1 = (const int*)d_in[1];
    const float* vals1 = (const float*)d_in[2];
    const float* x1    = (const float*)d_in[3];
    const int*   cols2 = (const int*)d_in[5];
    const float* vals2 = (const float*)d_in[6];
    const float* x2    = (const float*)d_in[7];
    const float* W1a = (const float*)d_in[8];
    const float* b1a = (const float*)d_in[9];
    const float* W1b = (const float*)d_in[10];
    const float* b1b = (const float*)d_in[11];
    const float* W2a = (const float*)d_in[12];
    const float* b2a = (const float*)d_in[13];
    const float* W2b = (const float*)d_in[14];
    const float* b2b = (const float*)d_in[15];
    const float* fc1_W = (const float*)d_in[16];
    const float* fc1_b = (const float*)d_in[17];
    const float* fc2_W = (const float*)d_in[18];
    const float* fc2_b = (const float*)d_in[19];
    const float* fc3_W = (const float*)d_in[20];
    const float* fc3_b = (const float*)d_in[21];
    float* out = (float*)d_out;

    float* feats = (float*)d_ws;   // NB*128 floats = 512 KB

    fused_branches<<<2 * NB, 256, 0, stream>>>(
        x1, cols1, vals1, W1a, b1a, W1b, b1b,
        x2, cols2, vals2, W2a, b2a, W2b, b2b, feats);

    mlp_head<<<NB / 8, 256, 0, stream>>>(feats, fc1_W, fc1_b, fc2_W, fc2_b,
                                         fc3_W, fc3_b, out);
}

// Round 5
// 493.901 us; speedup vs baseline: 1.7819x; 1.0850x over previous
//
#include <hip/hip_runtime.h>

#define NB 1024
#define N1P 116
#define N2P 200
#define HD 32

// ---------------------------------------------------------------------------
// Fully fused per-graph branch: one block = one graph.
// R5 fixes vs R4 (counter-driven):
//  * sSup/sH row stride 33 (was 32): stride-32 row-per-thread access put all
//    64 lanes on one bank quad (64-way conflict) -> 7.28M conflict cycles
//    measured; stride 33 spreads starts (tid+4k)%32, balanced.
//  * register double-buffer prefetch of next X chunk: overlap HBM latency
//    with FMA compute instead of exposing it at each barrier.
//  * __launch_bounds__(256,3): 3 blocks/CU (LDS 52.8 KB fits 3x).
// LDS: sSup[NP*33] + sH[NP*33]; X-stage (stride 20, balanced) aliases sSup.
// ---------------------------------------------------------------------------

template <int ST>
__device__ __forceinline__ void agg_phase(int base, int NPv,
                                          const int* __restrict__ cols,
                                          const float* __restrict__ vals,
                                          const float* __restrict__ sup,
                                          float bias, float* __restrict__ outh,
                                          int tid) {
    const int h = tid & 31;
    for (int n = tid >> 5; n < NPv; n += 8) {
        const int4* c4 = (const int4*)(cols + ((size_t)base + n) * 16);
        const float4* v4 = (const float4*)(vals + ((size_t)base + n) * 16);
        float a = bias;
#pragma unroll
        for (int q = 0; q < 4; ++q) {
            const int4 c = c4[q];
            const float4 v = v4[q];
            a += v.x * sup[(c.x - base) * ST + h];
            a += v.y * sup[(c.y - base) * ST + h];
            a += v.z * sup[(c.z - base) * ST + h];
            a += v.w * sup[(c.w - base) * ST + h];
        }
        outh[n * ST + h] = fmaxf(a, 0.f);
    }
}

template <int NP>
__device__ void branch_graph(int g,
                             const float* __restrict__ X,
                             const int* __restrict__ cols,
                             const float* __restrict__ vals,
                             const float* __restrict__ Wa,
                             const float* __restrict__ ba,
                             const float* __restrict__ Wb,
                             const float* __restrict__ bb,
                             float* __restrict__ feats, int foff,
                             float* sSup, float* sH) {
    constexpr int ST = 33;                 // row stride: bank-conflict-free
    constexpr int KC = 16;                 // k-chunk (floats)
    constexpr int SXS = 20;                // stage stride (balanced, verified)
    constexpr int NSLOT = NP * 4;          // float4 pieces per chunk
    constexpr int PSL = (NSLOT + 255) / 256;

    const int tid = threadIdx.x;
    const int base = g * NP;
    const float* xg = X + (size_t)base * NP;   // contiguous NP x NP block
    const float bA = ba[tid & 31];
    const float bB = bb[tid & 31];

    float* sX = sSup;                      // aliases support buffer

    float acc[32];
#pragma unroll
    for (int c = 0; c < 32; ++c) acc[c] = 0.f;

    const int NC = (NP + KC - 1) / KC;

    float4 cur[PSL], nxt[PSL];

    auto load_chunk = [&](int kc, float4* buf) {
        const int k0 = kc * KC;
        const int kw = (NP - k0) < KC ? (NP - k0) : KC;
        const int pieces = kw >> 2;
#pragma unroll
        for (int q = 0; q < PSL; ++q) {
            const int i = tid + q * 256;
            float4 v = make_float4(0.f, 0.f, 0.f, 0.f);
            if (i < NSLOT) {
                const int row = i >> 2, p = i & 3;
                if (p < pieces)
                    v = *(const float4*)(xg + (size_t)row * NP + k0 + p * 4);
            }
            buf[q] = v;
        }
    };
    auto store_chunk = [&](const float4* buf) {
#pragma unroll
        for (int q = 0; q < PSL; ++q) {
            const int i = tid + q * 256;
            if (i < NSLOT) {
                const int row = i >> 2, p = i & 3;
                *(float4*)&sX[row * SXS + p * 4] = buf[q];
            }
        }
    };

    load_chunk(0, cur);
#pragma unroll 1
    for (int kc = 0; kc < NC; ++kc) {
        __syncthreads();                 // sX region free for rewrite
        store_chunk(cur);
        __syncthreads();
        if (kc + 1 < NC) load_chunk(kc + 1, nxt);   // overlap with compute
        const int k0 = kc * KC;
        const int kw = (NP - k0) < KC ? (NP - k0) : KC;
        if (tid < NP) {
            const float* xrow = &sX[tid * SXS];
            const float* wb0 = Wa + (size_t)k0 * 32;
#pragma unroll 1
            for (int k4 = 0; k4 < kw; k4 += 4) {
                const float4 x4 = *(const float4*)&xrow[k4];
#pragma unroll
                for (int kk = 0; kk < 4; ++kk) {
                    const float xs = (&x4.x)[kk];
                    const float* w = wb0 + (k4 + kk) * 32;
#pragma unroll
                    for (int c4 = 0; c4 < 8; ++c4) {
                        const float4 wv = *(const float4*)&w[c4 * 4];
                        acc[c4 * 4 + 0] += xs * wv.x;
                        acc[c4 * 4 + 1] += xs * wv.y;
                        acc[c4 * 4 + 2] += xs * wv.z;
                        acc[c4 * 4 + 3] += xs * wv.w;
                    }
                }
            }
        }
#pragma unroll
        for (int q = 0; q < PSL; ++q) cur[q] = nxt[q];
    }
    __syncthreads();   // all compute done before support overwrites sX region

    if (tid < NP) {
#pragma unroll
        for (int c4 = 0; c4 < 8; ++c4) {
            float4 o;
            o.x = acc[c4 * 4 + 0]; o.y = acc[c4 * 4 + 1];
            o.z = acc[c4 * 4 + 2]; o.w = acc[c4 * 4 + 3];
            *(float4*)&sSup[tid * ST + c4 * 4] = o;
        }
    }
    __syncthreads();

    // ---- agg1 + relu -> sH ----
    agg_phase<ST>(base, NP, cols, vals, sSup, bA, sH, tid);
    __syncthreads();

    // ---- L2 GEMM: support2 = h1 @ Wb -> sSup ----
    if (tid < NP) {
        float acc2[32];
#pragma unroll
        for (int c = 0; c < 32; ++c) acc2[c] = 0.f;
        const float* xrow = &sH[tid * ST];
#pragma unroll 1
        for (int k4 = 0; k4 < 32; k4 += 4) {
            const float4 x4 = *(const float4*)&xrow[k4];
#pragma unroll
            for (int kk = 0; kk < 4; ++kk) {
                const float xs = (&x4.x)[kk];
                const float* w = Wb + (k4 + kk) * 32;
#pragma unroll
                for (int c4 = 0; c4 < 8; ++c4) {
                    const float4 wv = *(const float4*)&w[c4 * 4];
                    acc2[c4 * 4 + 0] += xs * wv.x;
                    acc2[c4 * 4 + 1] += xs * wv.y;
                    acc2[c4 * 4 + 2] += xs * wv.z;
                    acc2[c4 * 4 + 3] += xs * wv.w;
                }
            }
        }
#pragma unroll
        for (int c4 = 0; c4 < 8; ++c4) {
            float4 o;
            o.x = acc2[c4 * 4 + 0]; o.y = acc2[c4 * 4 + 1];
            o.z = acc2[c4 * 4 + 2]; o.w = acc2[c4 * 4 + 3];
            *(float4*)&sSup[tid * ST + c4 * 4] = o;
        }
    }
    __syncthreads();

    // ---- agg2 + relu -> sH ----
    agg_phase<ST>(base, NP, cols, vals, sSup, bB, sH, tid);
    __syncthreads();

    // ---- pool mean+max over nodes ----
    const int h = tid & 31, sl = tid >> 5;
    float sum = 0.f, mx = -1e30f;
    for (int n = sl; n < NP; n += 8) {
        const float v = sH[n * ST + h];
        sum += v;
        mx = fmaxf(mx, v);
    }
    float* sS = sSup;          // support2 dead
    float* sM = sSup + 256;
    sS[tid] = sum;
    sM[tid] = mx;
    __syncthreads();
    if (tid < 32) {
#pragma unroll
        for (int q = 1; q < 8; ++q) {
            sum += sS[tid + 32 * q];
            mx = fmaxf(mx, sM[tid + 32 * q]);
        }
        feats[(size_t)g * 128 + foff + tid] = sum * (1.0f / NP);
        feats[(size_t)g * 128 + foff + 32 + tid] = mx;
    }
}

__global__ __launch_bounds__(256, 3) void fused_branches(
        const float* __restrict__ x1, const int* __restrict__ cols1,
        const float* __restrict__ vals1,
        const float* __restrict__ W1a, const float* __restrict__ b1a,
        const float* __restrict__ W1b, const float* __restrict__ b1b,
        const float* __restrict__ x2, const int* __restrict__ cols2,
        const float* __restrict__ vals2,
        const float* __restrict__ W2a, const float* __restrict__ b2a,
        const float* __restrict__ W2b, const float* __restrict__ b2b,
        float* __restrict__ feats) {
    __shared__ float sSup[N2P * 33];   // 26.4 KB
    __shared__ float sH[N2P * 33];     // 26.4 KB  (52.8 KB -> 3 blocks/CU)
    const int bid = blockIdx.x;
    if (bid < NB) {
        branch_graph<N1P>(bid, x1, cols1, vals1, W1a, b1a, W1b, b1b, feats, 0,
                          sSup, sH);
    } else {
        branch_graph<N2P>(bid - NB, x2, cols2, vals2, W2a, b2a, W2b, b2b, feats,
                          64, sSup, sH);
    }
}

// ---------------------------------------------------------------------------
// MLP head: [B,128] -> relu(fc1) -> relu(fc2) -> fc3 -> [B,2]
// ---------------------------------------------------------------------------
__global__ __launch_bounds__(256) void mlp_head(const float* __restrict__ feats,
                                                const float* __restrict__ W1,
                                                const float* __restrict__ b1,
                                                const float* __restrict__ W2,
                                                const float* __restrict__ b2,
                                                const float* __restrict__ W3,
                                                const float* __restrict__ b3,
                                                float* __restrict__ out) {
    __shared__ float sW1[128 * 32];
    __shared__ float sW2[32 * 16];
    __shared__ float sW3[16 * 2];
    __shared__ float sB1[32], sB2[16], sB3[2];
    __shared__ float sF[8 * 128];
    __shared__ float sH1[8 * 32];
    __shared__ float sH2[8 * 16];

    const int tid = threadIdx.x;
    for (int idx = tid; idx < 128 * 32; idx += 256) sW1[idx] = W1[idx];
    for (int idx = tid; idx < 32 * 16; idx += 256) sW2[idx] = W2[idx];
    if (tid < 32) { sW3[tid] = W3[tid]; sB1[tid] = b1[tid]; }
    if (tid < 16) sB2[tid] = b2[tid];
    if (tid < 2) sB3[tid] = b3[tid];
    const long g0 = (long)blockIdx.x * 8;
    for (int idx = tid; idx < 1024; idx += 256) sF[idx] = feats[g0 * 128 + idx];
    __syncthreads();

    const int g = tid >> 5, h = tid & 31;
    float a1 = sB1[h];
#pragma unroll 4
    for (int k = 0; k < 128; ++k) a1 += sF[g * 128 + k] * sW1[k * 32 + h];
    sH1[g * 32 + h] = fmaxf(a1, 0.f);
    __syncthreads();

    if (h < 16) {
        float a2 = sB2[h];
#pragma unroll
        for (int k = 0; k < 32; ++k) a2 += sH1[g * 32 + k] * sW2[k * 16 + h];
        sH2[g * 16 + h] = fmaxf(a2, 0.f);
    }
    __syncthreads();

    if (h < 2) {
        float a3 = sB3[h];
#pragma unroll
        for (int k = 0; k < 16; ++k) a3 += sH2[g * 16 + k] * sW3[k * 2 + h];
        out[(g0 + g) * 2 + h] = a3;
    }
}

// ---------------------------------------------------------------------------
extern "C" void kernel_launch(void* const* d_in, const int* in_sizes, int n_in,
                              void* d_out, int out_size, void* d_ws, size_t ws_size,
                              hipStream_t stream) {
    const int*   cols1 = (const int*)d_in[1];
    const float* vals1 = (const float*)d_in[2];
    const float* x1    = (const float*)d_in[3];
    const int*   cols2 = (const int*)d_in[5];
    const float* vals2 = (const float*)d_in[6];
    const float* x2    = (const float*)d_in[7];
    const float* W1a = (const float*)d_in[8];
    const float* b1a = (const float*)d_in[9];
    const float* W1b = (const float*)d_in[10];
    const float* b1b = (const float*)d_in[11];
    const float* W2a = (const float*)d_in[12];
    const float* b2a = (const float*)d_in[13];
    const float* W2b = (const float*)d_in[14];
    const float* b2b = (const float*)d_in[15];
    const float* fc1_W = (const float*)d_in[16];
    const float* fc1_b = (const float*)d_in[17];
    const float* fc2_W = (const float*)d_in[18];
    const float* fc2_b = (const float*)d_in[19];
    const float* fc3_W = (const float*)d_in[20];
    const float* fc3_b = (const float*)d_in[21];
    float* out = (float*)d_out;

    float* feats = (float*)d_ws;   // NB*128 floats = 512 KB

    fused_branches<<<2 * NB, 256, 0, stream>>>(
        x1, cols1, vals1, W1a, b1a, W1b, b1b,
        x2, cols2, vals2, W2a, b2a, W2b, b2b, feats);

    mlp_head<<<NB / 8, 256, 0, stream>>>(feats, fc1_W, fc1_b, fc2_W, fc2_b,
                                         fc3_W, fc3_b, out);
}